// Round 6
// baseline (1565.388 us; speedup 1.0000x reference)
//
#include <hip/hip_runtime.h>

#define NB 4096
#define NT 512
#define NI 25
#define NH 20
#define NL 10
#define CH 32

typedef float f4 __attribute__((ext_vector_type(4)));

#if __has_builtin(__builtin_amdgcn_rcpf)
__device__ __forceinline__ float rcpf(float x){ return __builtin_amdgcn_rcpf(x); }
#else
__device__ __forceinline__ float rcpf(float x){ return 1.0f/x; }
#endif

struct Smem {
  float xbuf[CH][28];   // rows 112B (16B-aligned); [25..27] zeroed
  float hbuf[24];       // h[0..19]
  float gbuf[132];      // gate G=5k+g at k*8+g
  float zbuf[12];
};

// Combined operand vector v[48] = {x[0..24], 0,0,0, h[0..19]}, split 12 per p-group.
__device__ __forceinline__ void load_weights(
    const float* __restrict__ Wih, const float* __restrict__ Whh,
    const float* __restrict__ bih, const float* __restrict__ bhh,
    int p, int k, float (&w)[5][12], float (&bias)[5])
{
#pragma unroll
  for (int g=0; g<5; ++g){
    const int G = 5*k+g;
    const float* wi = Wih + G*25;
    const float* wh = Whh + G*20;
    if (p==0){
#pragma unroll
      for (int j=0;j<12;++j) w[g][j] = wi[j];
      bias[g] = bih[G] + bhh[G];
    } else if (p==1){
#pragma unroll
      for (int j=0;j<12;++j) w[g][j] = wi[12+j];
      bias[g] = 0.f;
    } else if (p==2){
      w[g][0]=wi[24]; w[g][1]=0.f; w[g][2]=0.f; w[g][3]=0.f;
#pragma unroll
      for (int j=0;j<8;++j) w[g][4+j] = wh[j];
      bias[g] = 0.f;
    } else {
#pragma unroll
      for (int j=0;j<12;++j) w[g][j] = wh[8+j];
      bias[g] = 0.f;
    }
  }
}

template<bool DEC>
__device__ __forceinline__ void lstm_loop(
    const float* __restrict__ xrow,   // x + b*NT*NI
    Smem* sm, int lane, int p, int k,
    const float (&w)[5][12], const float (&bias)[5], float& c,
    const float (&ow)[20], float obias,
    float* __restrict__ xhat)         // out + b*NT*NI
{
  const bool is_g = ((k>>2)==2);
  const float gmul = is_g ? -2.0f : -1.0f;
  const int lin = lane;
  const int ai  = (lin/5)*8 + (lin%5);           // gbuf addr of i-gate, unit lin
  const float* xb0 = &sm->xbuf[0][0];
  const float* hb  = &sm->hbuf[0];
  // slice base pointers per p-group (see layout comment above)
  const float* b1 = (p==3) ? hb+8  : xb0 + 12*p;
  const float* b2 = (p< 2) ? xb0 + 4 + 12*p : ((p==2) ? hb+0  : hb+12);
  const float* b3 = (p< 2) ? xb0 + 8 + 12*p : ((p==2) ? hb+4  : hb+16);
  const int m1  = (p<3) ? ~0 : 0;                // slice1 advances with tc unless p==3
  const int m23 = (p<2) ? ~0 : 0;                // slices 2,3 advance only for p<2

  for (int t=0; t<NT; ++t){
    const int tc = t & (CH-1);
    if (tc == 0){
      __syncthreads();
      const float* gsrc = xrow + (size_t)t*NI;
#pragma unroll
      for (int it=0; it<14; ++it){               // 896 slots / 64 lanes
        int idx = lane + it*64;
        int tt = idx/28, ii = idx - tt*28;
        sm->xbuf[tt][ii] = (ii < NI) ? gsrc[tt*NI + ii] : 0.f;
      }
      __syncthreads();
    }
    const int off = tc*28;
    f4 v1 = *(const f4*)(b1 + (off & m1));
    f4 v2 = *(const f4*)(b2 + (off & m23));
    f4 v3 = *(const f4*)(b3 + (off & m23));

    float acc[5];
#pragma unroll
    for (int g=0; g<5; ++g) acc[g] = bias[g];
#pragma unroll
    for (int g=0; g<5; ++g){
      acc[g]=fmaf(w[g][0] ,v1.x,acc[g]); acc[g]=fmaf(w[g][1] ,v1.y,acc[g]);
      acc[g]=fmaf(w[g][2] ,v1.z,acc[g]); acc[g]=fmaf(w[g][3] ,v1.w,acc[g]);
      acc[g]=fmaf(w[g][4] ,v2.x,acc[g]); acc[g]=fmaf(w[g][5] ,v2.y,acc[g]);
      acc[g]=fmaf(w[g][6] ,v2.z,acc[g]); acc[g]=fmaf(w[g][7] ,v2.w,acc[g]);
      acc[g]=fmaf(w[g][8] ,v3.x,acc[g]); acc[g]=fmaf(w[g][9] ,v3.y,acc[g]);
      acc[g]=fmaf(w[g][10],v3.z,acc[g]); acc[g]=fmaf(w[g][11],v3.w,acc[g]);
    }
#pragma unroll
    for (int g=0; g<5; ++g){
      acc[g] += __shfl_xor(acc[g], 16);
      acc[g] += __shfl_xor(acc[g], 32);
    }
    if (p==0){
      float val[5];
#pragma unroll
      for (int g=0; g<5; ++g){
        float e = __expf(gmul*acc[g]);
        float s = rcpf(1.0f + e);
        val[g] = is_g ? (2.0f*s - 1.0f) : s;
      }
      f4 v; v.x=val[0]; v.y=val[1]; v.z=val[2]; v.w=val[3];
      *(f4*)&sm->gbuf[k*8] = v;
      sm->gbuf[k*8+4] = val[4];
    }
    __syncthreads();
    if (lin < NH){
      float ig = sm->gbuf[ai];
      float fg = sm->gbuf[ai+32];
      float gg = sm->gbuf[ai+64];
      float og = sm->gbuf[ai+96];
      float cn = fmaf(fg, c, ig*gg);
      c = cn;
      float e  = __expf(-2.0f*cn);
      float th = 2.0f*rcpf(1.0f + e) - 1.0f;     // NaN-safe tanh
      sm->hbuf[lin] = og*th;
    }
    __syncthreads();
    if (DEC && lin < NI){
      f4 h0_=*(const f4*)(hb+0),  h1_=*(const f4*)(hb+4),  h2_=*(const f4*)(hb+8);
      f4 h3_=*(const f4*)(hb+12), h4_=*(const f4*)(hb+16);
      float a = obias;
      a=fmaf(ow[0] ,h0_.x,a); a=fmaf(ow[1] ,h0_.y,a); a=fmaf(ow[2] ,h0_.z,a); a=fmaf(ow[3] ,h0_.w,a);
      a=fmaf(ow[4] ,h1_.x,a); a=fmaf(ow[5] ,h1_.y,a); a=fmaf(ow[6] ,h1_.z,a); a=fmaf(ow[7] ,h1_.w,a);
      a=fmaf(ow[8] ,h2_.x,a); a=fmaf(ow[9] ,h2_.y,a); a=fmaf(ow[10],h2_.z,a); a=fmaf(ow[11],h2_.w,a);
      a=fmaf(ow[12],h3_.x,a); a=fmaf(ow[13],h3_.y,a); a=fmaf(ow[14],h3_.z,a); a=fmaf(ow[15],h3_.w,a);
      a=fmaf(ow[16],h4_.x,a); a=fmaf(ow[17],h4_.y,a); a=fmaf(ow[18],h4_.z,a); a=fmaf(ow[19],h4_.w,a);
      xhat[(size_t)t*NI + lin] = a;
    }
  }
}

__global__ __launch_bounds__(64)
__attribute__((amdgpu_waves_per_eu(4,4)))    // pin: no occupancy over-shoot, VGPR budget 128
void lstm_vae_kernel(
  const float* __restrict__ x, const float* __restrict__ h0, const float* __restrict__ c0,
  const float* __restrict__ noise,
  const float* __restrict__ eWih, const float* __restrict__ eWhh, const float* __restrict__ ebih, const float* __restrict__ ebhh,
  const float* __restrict__ dWih, const float* __restrict__ dWhh, const float* __restrict__ dbih, const float* __restrict__ dbhh,
  const float* __restrict__ mW, const float* __restrict__ mb,
  const float* __restrict__ lW, const float* __restrict__ lb,
  const float* __restrict__ iW, const float* __restrict__ ib,
  const float* __restrict__ oW, const float* __restrict__ ob,
  float* __restrict__ out)
{
  __shared__ Smem sm;
  const int lane = threadIdx.x;
  const int p = lane>>4, k = lane&15, lin = lane;
  const int b = blockIdx.x;
  const float* xrow = x + (size_t)b*NT*NI;

  float w[5][12], bias[5];
  float ow[20]; float obias = 0.f;
#pragma unroll
  for (int j=0;j<20;++j) ow[j] = 0.f;
  float c = 0.f;

  if (lin < NH){
    sm.hbuf[lin] = h0[(size_t)b*NH + lin];
    c = c0[(size_t)b*NH + lin];
  }
  if (lin >= NH && lin < 24) sm.hbuf[lin] = 0.f;
  load_weights(eWih, eWhh, ebih, ebhh, p, k, w, bias);
  __syncthreads();

  lstm_loop<false>(xrow, &sm, lane, p, k, w, bias, c, ow, obias, nullptr);

  const size_t OFF1 = (size_t)NB*NT*NI;
  const size_t OFF2 = OFF1 + (size_t)NB*NL;
  const size_t OFF3 = OFF2 + (size_t)NB*NL;
  const size_t OFF4 = OFF3 + (size_t)NB*NL;
  const size_t OFF5 = OFF4 + (size_t)NB*NH;

  if (lin < NH){
    out[OFF4 + (size_t)b*NH + lin] = sm.hbuf[lin];
    out[OFF5 + (size_t)b*NH + lin] = c;
  }
  if (lin < NL){
    float h[20];
#pragma unroll
    for (int j=0;j<20;++j) h[j] = sm.hbuf[j];
    float mm = mb[lin], lv = lb[lin];
#pragma unroll
    for (int j=0;j<20;++j){
      mm = fmaf(mW[lin*20+j], h[j], mm);
      lv = fmaf(lW[lin*20+j], h[j], lv);
    }
    float sd = __expf(0.5f*lv);
    float zz = fmaf(noise[(size_t)b*NL + lin], sd, mm);
    out[OFF1 + (size_t)b*NL + lin] = mm;
    out[OFF2 + (size_t)b*NL + lin] = lv;
    out[OFF3 + (size_t)b*NL + lin] = zz;
    sm.zbuf[lin] = zz;
  }
  __syncthreads();
  if (lin < NH){
    float hd = ib[lin];
#pragma unroll
    for (int l=0;l<NL;++l) hd = fmaf(iW[lin*NL+l], sm.zbuf[l], hd);
    c = hd;
    sm.hbuf[lin] = hd;
  }
  load_weights(dWih, dWhh, dbih, dbhh, p, k, w, bias);
  if (lin < NI){
#pragma unroll
    for (int j=0;j<20;++j) ow[j] = oW[lin*20+j];
    obias = ob[lin];
  }
  __syncthreads();

  lstm_loop<true>(xrow, &sm, lane, p, k, w, bias, c, ow, obias,
                  out + (size_t)b*NT*NI);
}

extern "C" void kernel_launch(void* const* d_in, const int* in_sizes, int n_in,
                              void* d_out, int out_size, void* d_ws, size_t ws_size,
                              hipStream_t stream) {
  const float* x     = (const float*)d_in[0];
  const float* h0    = (const float*)d_in[1];
  const float* c0    = (const float*)d_in[2];
  const float* noise = (const float*)d_in[3];
  const float* eWih  = (const float*)d_in[4];
  const float* eWhh  = (const float*)d_in[5];
  const float* ebih  = (const float*)d_in[6];
  const float* ebhh  = (const float*)d_in[7];
  const float* dWih  = (const float*)d_in[8];
  const float* dWhh  = (const float*)d_in[9];
  const float* dbih  = (const float*)d_in[10];
  const float* dbhh  = (const float*)d_in[11];
  const float* mW    = (const float*)d_in[12];
  const float* mb    = (const float*)d_in[13];
  const float* lW    = (const float*)d_in[14];
  const float* lb    = (const float*)d_in[15];
  const float* iW    = (const float*)d_in[16];
  const float* ib    = (const float*)d_in[17];
  const float* oW    = (const float*)d_in[18];
  const float* ob    = (const float*)d_in[19];
  float* out = (float*)d_out;

  hipLaunchKernelGGL(lstm_vae_kernel, dim3(NB), dim3(64), 0, stream,
                     x, h0, c0, noise,
                     eWih, eWhh, ebih, ebhh,
                     dWih, dWhh, dbih, dbhh,
                     mW, mb, lW, lb, iW, ib, oW, ob, out);
}

// Round 7
// 1353.434 us; speedup vs baseline: 1.1566x; 1.1566x over previous
//
#include <hip/hip_runtime.h>

#define NB 4096
#define NT 512
#define NI 25
#define NH 20
#define NL 10
#define CH 32

typedef float f4 __attribute__((ext_vector_type(4)));

#if __has_builtin(__builtin_amdgcn_rcpf)
__device__ __forceinline__ float rcpf(float x){ return __builtin_amdgcn_rcpf(x); }
#else
__device__ __forceinline__ float rcpf(float x){ return 1.0f/x; }
#endif

// Value anchors: make loaded values opaque so the scheduler cannot
// rematerialize the loads inside the timestep loop (rounds 4-6 disease).
__device__ __forceinline__ void anchor(float &x){ asm volatile("" : "+v"(x)); }
__device__ __forceinline__ void anchor_w(float (&w)[5][12], float (&bias)[5]){
#pragma unroll
  for (int g=0;g<5;++g){
#pragma unroll
    for (int j=0;j<12;++j) anchor(w[g][j]);
    anchor(bias[g]);
  }
}

struct Smem {
  float xbuf[CH][28];   // rows 112B (16B-aligned); [25..27] zeroed
  float hbuf[24];       // h[0..19]
  float gbuf[132];      // gate G=5k+g at k*8+g
  float zbuf[12];
};

// Combined operand vector v[48] = {x[0..24], 0,0,0, h[0..19]}, split 12 per p-group.
__device__ __forceinline__ void load_weights(
    const float* __restrict__ Wih, const float* __restrict__ Whh,
    const float* __restrict__ bih, const float* __restrict__ bhh,
    int p, int k, float (&w)[5][12], float (&bias)[5])
{
#pragma unroll
  for (int g=0; g<5; ++g){
    const int G = 5*k+g;
    const float* wi = Wih + G*25;
    const float* wh = Whh + G*20;
    if (p==0){
#pragma unroll
      for (int j=0;j<12;++j) w[g][j] = wi[j];
      bias[g] = bih[G] + bhh[G];
    } else if (p==1){
#pragma unroll
      for (int j=0;j<12;++j) w[g][j] = wi[12+j];
      bias[g] = 0.f;
    } else if (p==2){
      w[g][0]=wi[24]; w[g][1]=0.f; w[g][2]=0.f; w[g][3]=0.f;
#pragma unroll
      for (int j=0;j<8;++j) w[g][4+j] = wh[j];
      bias[g] = 0.f;
    } else {
#pragma unroll
      for (int j=0;j<12;++j) w[g][j] = wh[8+j];
      bias[g] = 0.f;
    }
  }
}

template<bool DEC>
__device__ __forceinline__ void lstm_loop(
    const float* __restrict__ xrow,   // x + b*NT*NI
    Smem* sm, int lane, int p, int k,
    const float (&w)[5][12], const float (&bias)[5], float& c,
    const float (&ow)[20], float obias,
    float* __restrict__ xhat)         // out + b*NT*NI
{
  const bool is_g = ((k>>2)==2);
  const float gmul = is_g ? -2.0f : -1.0f;
  const int lin = lane;
  const int ai  = (lin/5)*8 + (lin%5);           // gbuf addr of i-gate, unit lin
  const float* xb0 = &sm->xbuf[0][0];
  const float* hb  = &sm->hbuf[0];
  // slice base pointers per p-group (see layout comment above)
  const float* b1 = (p==3) ? hb+8  : xb0 + 12*p;
  const float* b2 = (p< 2) ? xb0 + 4 + 12*p : ((p==2) ? hb+0  : hb+12);
  const float* b3 = (p< 2) ? xb0 + 8 + 12*p : ((p==2) ? hb+4  : hb+16);
  const int m1  = (p<3) ? ~0 : 0;                // slice1 advances with tc unless p==3
  const int m23 = (p<2) ? ~0 : 0;                // slices 2,3 advance only for p<2

  for (int t=0; t<NT; ++t){
    const int tc = t & (CH-1);
    if (tc == 0){
      __syncthreads();
      const float* gsrc = xrow + (size_t)t*NI;
#pragma unroll
      for (int it=0; it<14; ++it){               // 896 slots / 64 lanes
        int idx = lane + it*64;
        int tt = idx/28, ii = idx - tt*28;
        sm->xbuf[tt][ii] = (ii < NI) ? gsrc[tt*NI + ii] : 0.f;
      }
      __syncthreads();
    }
    const int off = tc*28;
    f4 v1 = *(const f4*)(b1 + (off & m1));
    f4 v2 = *(const f4*)(b2 + (off & m23));
    f4 v3 = *(const f4*)(b3 + (off & m23));

    float acc[5];
#pragma unroll
    for (int g=0; g<5; ++g) acc[g] = bias[g];
#pragma unroll
    for (int g=0; g<5; ++g){
      acc[g]=fmaf(w[g][0] ,v1.x,acc[g]); acc[g]=fmaf(w[g][1] ,v1.y,acc[g]);
      acc[g]=fmaf(w[g][2] ,v1.z,acc[g]); acc[g]=fmaf(w[g][3] ,v1.w,acc[g]);
      acc[g]=fmaf(w[g][4] ,v2.x,acc[g]); acc[g]=fmaf(w[g][5] ,v2.y,acc[g]);
      acc[g]=fmaf(w[g][6] ,v2.z,acc[g]); acc[g]=fmaf(w[g][7] ,v2.w,acc[g]);
      acc[g]=fmaf(w[g][8] ,v3.x,acc[g]); acc[g]=fmaf(w[g][9] ,v3.y,acc[g]);
      acc[g]=fmaf(w[g][10],v3.z,acc[g]); acc[g]=fmaf(w[g][11],v3.w,acc[g]);
    }
#pragma unroll
    for (int g=0; g<5; ++g){
      acc[g] += __shfl_xor(acc[g], 16);
      acc[g] += __shfl_xor(acc[g], 32);
    }
    if (p==0){
      float val[5];
#pragma unroll
      for (int g=0; g<5; ++g){
        float e = __expf(gmul*acc[g]);
        float s = rcpf(1.0f + e);
        val[g] = is_g ? (2.0f*s - 1.0f) : s;
      }
      f4 v; v.x=val[0]; v.y=val[1]; v.z=val[2]; v.w=val[3];
      *(f4*)&sm->gbuf[k*8] = v;
      sm->gbuf[k*8+4] = val[4];
    }
    __syncthreads();
    if (lin < NH){
      float ig = sm->gbuf[ai];
      float fg = sm->gbuf[ai+32];
      float gg = sm->gbuf[ai+64];
      float og = sm->gbuf[ai+96];
      float cn = fmaf(fg, c, ig*gg);
      c = cn;
      float e  = __expf(-2.0f*cn);
      float th = 2.0f*rcpf(1.0f + e) - 1.0f;     // NaN-safe tanh
      sm->hbuf[lin] = og*th;
    }
    __syncthreads();
    if (DEC && lin < NI){
      f4 h0_=*(const f4*)(hb+0),  h1_=*(const f4*)(hb+4),  h2_=*(const f4*)(hb+8);
      f4 h3_=*(const f4*)(hb+12), h4_=*(const f4*)(hb+16);
      float a = obias;
      a=fmaf(ow[0] ,h0_.x,a); a=fmaf(ow[1] ,h0_.y,a); a=fmaf(ow[2] ,h0_.z,a); a=fmaf(ow[3] ,h0_.w,a);
      a=fmaf(ow[4] ,h1_.x,a); a=fmaf(ow[5] ,h1_.y,a); a=fmaf(ow[6] ,h1_.z,a); a=fmaf(ow[7] ,h1_.w,a);
      a=fmaf(ow[8] ,h2_.x,a); a=fmaf(ow[9] ,h2_.y,a); a=fmaf(ow[10],h2_.z,a); a=fmaf(ow[11],h2_.w,a);
      a=fmaf(ow[12],h3_.x,a); a=fmaf(ow[13],h3_.y,a); a=fmaf(ow[14],h3_.z,a); a=fmaf(ow[15],h3_.w,a);
      a=fmaf(ow[16],h4_.x,a); a=fmaf(ow[17],h4_.y,a); a=fmaf(ow[18],h4_.z,a); a=fmaf(ow[19],h4_.w,a);
      xhat[(size_t)t*NI + lin] = a;
    }
  }
}

__global__ __launch_bounds__(64)
__attribute__((amdgpu_waves_per_eu(4,4)))    // VGPR budget 128; anchors force residency
void lstm_vae_kernel(
  const float* __restrict__ x, const float* __restrict__ h0, const float* __restrict__ c0,
  const float* __restrict__ noise,
  const float* __restrict__ eWih, const float* __restrict__ eWhh, const float* __restrict__ ebih, const float* __restrict__ ebhh,
  const float* __restrict__ dWih, const float* __restrict__ dWhh, const float* __restrict__ dbih, const float* __restrict__ dbhh,
  const float* __restrict__ mW, const float* __restrict__ mb,
  const float* __restrict__ lW, const float* __restrict__ lb,
  const float* __restrict__ iW, const float* __restrict__ ib,
  const float* __restrict__ oW, const float* __restrict__ ob,
  float* __restrict__ out)
{
  __shared__ Smem sm;
  const int lane = threadIdx.x;
  const int p = lane>>4, k = lane&15, lin = lane;
  const int b = blockIdx.x;
  const float* xrow = x + (size_t)b*NT*NI;

  float w[5][12], bias[5];
  float ow[20]; float obias = 0.f;
#pragma unroll
  for (int j=0;j<20;++j) ow[j] = 0.f;
  float c = 0.f;

  if (lin < NH){
    sm.hbuf[lin] = h0[(size_t)b*NH + lin];
    c = c0[(size_t)b*NH + lin];
  }
  if (lin >= NH && lin < 24) sm.hbuf[lin] = 0.f;
  load_weights(eWih, eWhh, ebih, ebhh, p, k, w, bias);
  anchor_w(w, bias);                 // opaque: no remat inside enc loop
  __syncthreads();

  lstm_loop<false>(xrow, &sm, lane, p, k, w, bias, c, ow, obias, nullptr);

  const size_t OFF1 = (size_t)NB*NT*NI;
  const size_t OFF2 = OFF1 + (size_t)NB*NL;
  const size_t OFF3 = OFF2 + (size_t)NB*NL;
  const size_t OFF4 = OFF3 + (size_t)NB*NL;
  const size_t OFF5 = OFF4 + (size_t)NB*NH;

  if (lin < NH){
    out[OFF4 + (size_t)b*NH + lin] = sm.hbuf[lin];
    out[OFF5 + (size_t)b*NH + lin] = c;
  }
  if (lin < NL){
    float h[20];
#pragma unroll
    for (int j=0;j<20;++j) h[j] = sm.hbuf[j];
    float mm = mb[lin], lv = lb[lin];
#pragma unroll
    for (int j=0;j<20;++j){
      mm = fmaf(mW[lin*20+j], h[j], mm);
      lv = fmaf(lW[lin*20+j], h[j], lv);
    }
    float sd = __expf(0.5f*lv);
    float zz = fmaf(noise[(size_t)b*NL + lin], sd, mm);
    out[OFF1 + (size_t)b*NL + lin] = mm;
    out[OFF2 + (size_t)b*NL + lin] = lv;
    out[OFF3 + (size_t)b*NL + lin] = zz;
    sm.zbuf[lin] = zz;
  }
  __syncthreads();
  if (lin < NH){
    float hd = ib[lin];
#pragma unroll
    for (int l=0;l<NL;++l) hd = fmaf(iW[lin*NL+l], sm.zbuf[l], hd);
    c = hd;
    sm.hbuf[lin] = hd;
  }
  load_weights(dWih, dWhh, dbih, dbhh, p, k, w, bias);
  anchor_w(w, bias);                 // opaque: no remat inside dec loop
  if (lin < NI){
#pragma unroll
    for (int j=0;j<20;++j) ow[j] = oW[lin*20+j];
    obias = ob[lin];
  }
#pragma unroll
  for (int j=0;j<20;++j) anchor(ow[j]);
  anchor(obias);
  __syncthreads();

  lstm_loop<true>(xrow, &sm, lane, p, k, w, bias, c, ow, obias,
                  out + (size_t)b*NT*NI);
}

extern "C" void kernel_launch(void* const* d_in, const int* in_sizes, int n_in,
                              void* d_out, int out_size, void* d_ws, size_t ws_size,
                              hipStream_t stream) {
  const float* x     = (const float*)d_in[0];
  const float* h0    = (const float*)d_in[1];
  const float* c0    = (const float*)d_in[2];
  const float* noise = (const float*)d_in[3];
  const float* eWih  = (const float*)d_in[4];
  const float* eWhh  = (const float*)d_in[5];
  const float* ebih  = (const float*)d_in[6];
  const float* ebhh  = (const float*)d_in[7];
  const float* dWih  = (const float*)d_in[8];
  const float* dWhh  = (const float*)d_in[9];
  const float* dbih  = (const float*)d_in[10];
  const float* dbhh  = (const float*)d_in[11];
  const float* mW    = (const float*)d_in[12];
  const float* mb    = (const float*)d_in[13];
  const float* lW    = (const float*)d_in[14];
  const float* lb    = (const float*)d_in[15];
  const float* iW    = (const float*)d_in[16];
  const float* ib    = (const float*)d_in[17];
  const float* oW    = (const float*)d_in[18];
  const float* ob    = (const float*)d_in[19];
  float* out = (float*)d_out;

  hipLaunchKernelGGL(lstm_vae_kernel, dim3(NB), dim3(64), 0, stream,
                     x, h0, c0, noise,
                     eWih, eWhh, ebih, ebhh,
                     dWih, dWhh, dbih, dbhh,
                     mW, mb, lW, lb, iW, ib, oW, ob, out);
}

// Round 8
// 1038.474 us; speedup vs baseline: 1.5074x; 1.3033x over previous
//
#include <hip/hip_runtime.h>

#define NB 4096
#define NT 512
#define NI 25
#define NH 20
#define NL 10
#define CHK 16

typedef unsigned int u32;
typedef _Float16 h2v __attribute__((ext_vector_type(2)));
typedef float f4v __attribute__((ext_vector_type(4)));

__device__ __forceinline__ float rcpf(float x){
#if __has_builtin(__builtin_amdgcn_rcpf)
  return __builtin_amdgcn_rcpf(x);
#else
  return 1.0f/x;
#endif
}
__device__ __forceinline__ float exp2_fast(float x){
  float r; asm("v_exp_f32 %0, %1" : "=v"(r) : "v"(x)); return r;
}
__device__ __forceinline__ u32 pk(float a, float b){
  return __builtin_bit_cast(u32, __builtin_amdgcn_cvt_pkrtz(a, b));
}
__device__ __forceinline__ float fdot2(u32 a, u32 b, float c){
#if __has_builtin(__builtin_amdgcn_fdot2)
  return __builtin_amdgcn_fdot2(__builtin_bit_cast(h2v,a), __builtin_bit_cast(h2v,b), c, false);
#else
  h2v av = __builtin_bit_cast(h2v,a), bv = __builtin_bit_cast(h2v,b);
  return fmaf((float)av.x,(float)bv.x, fmaf((float)av.y,(float)bv.y, c));
#endif
}
__device__ __forceinline__ void anchor_u(u32 &x){ asm volatile("" : "+v"(x)); }
__device__ __forceinline__ void anchor_f(float &x){ asm volatile("" : "+v"(x)); }

// LDS: per step t%16, pair-dwords [0..13] = x[0..24]+3 zero pads (f16 pairs),
// [14..23] = h[0..19] (f16 pairs, rewritten every step), [24..25] pad.
struct Smem {
  u32   xp[CHK][26];
  float gbuf[132];   // gate G=5k+g at k*8+g
  float zbuf[12];
};

// Combined operand positions: s in [0,48): s<25 -> x[s]; s<28 -> 0; else h[s-28].
// Lane (p,k): owns gates G=5k..5k+4, positions 12p..12p+11 (6 f16 pairs).
__device__ __forceinline__ void load_w(
    const float* __restrict__ Wih, const float* __restrict__ Whh,
    const float* __restrict__ bih, const float* __restrict__ bhh,
    int p, int k, float SC, u32 (&w2)[5][6], float (&bias)[5])
{
#pragma unroll
  for (int g=0; g<5; ++g){
    const int G = 5*k+g;
    const float* wi = Wih + G*25;
    const float* wh = Whh + G*20;
#pragma unroll
    for (int j=0; j<6; ++j){
      const int s0 = 12*p + 2*j, s1 = s0+1;
      float a = (s0<25) ? wi[s0] : ((s0<28) ? 0.f : wh[s0-28]);
      float b = (s1<25) ? wi[s1] : ((s1<28) ? 0.f : wh[s1-28]);
      w2[g][j] = pk(a*SC, b*SC);
      anchor_u(w2[g][j]);
    }
    bias[g] = (p==0) ? SC*(bih[G]+bhh[G]) : 0.f;
    anchor_f(bias[g]);
  }
}

template<bool DEC>
__device__ __forceinline__ void lstm_loop(
    const float* __restrict__ xrow, Smem* sm, int lane, int p, int k,
    const u32 (&w2)[5][6], const float (&bias)[5], float& c,
    const u32 (&ow2)[10], float obias, float* __restrict__ xhat)
{
  const bool is_g = ((k>>2)==2);
  const int lin = lane;
  const int ai  = (lin/5)*8 + (lin%5);
  const float TC2 = -2.8853900817779268f;   // -2*log2(e)

  for (int t=0; t<NT; ++t){
    const int tc = t & (CHK-1);
    if (tc == 0){
      __syncthreads();                       // old chunk fully consumed
      const float* gsrc = xrow + (size_t)t*NI;
#pragma unroll
      for (int it=0; it<4; ++it){
        int P = lane + it*64;                // 224 pairs = 16 steps x 14
        if (P < 14*CHK){
          int tt = P/14, pr = P - tt*14;
          int i0 = 2*pr, i1 = i0+1;
          float a = (i0<NI) ? gsrc[tt*NI+i0] : 0.f;
          float b = (i1<NI) ? gsrc[tt*NI+i1] : 0.f;
          sm->xp[tt][pr] = pk(a,b);
        }
      }
    }
    __syncthreads();                         // orders h-write(t-1) + staging -> reads

    if (DEC && t>0 && lin<NI){
      // project h after step t-1 (h pairs of row tc were written at end of t-1)
      const u32* hp = &sm->xp[tc][14];
      float a = obias;
#pragma unroll
      for (int j=0;j<10;++j) a = fdot2(ow2[j], hp[j], a);
      xhat[(size_t)(t-1)*NI + lin] = a;
    }

    // uniform operand slice: 6 pair-dwords at xp[tc][6p .. 6p+5]
    const u32* opb = &sm->xp[tc][6*p];
    u32 op[6];
    *(uint2*)&op[0] = *(const uint2*)(opb+0);
    *(uint2*)&op[2] = *(const uint2*)(opb+2);
    *(uint2*)&op[4] = *(const uint2*)(opb+4);

    float acc[5];
#pragma unroll
    for (int g=0; g<5; ++g){
      float a = bias[g];
#pragma unroll
      for (int j=0; j<6; ++j) a = fdot2(w2[g][j], op[j], a);
      acc[g] = a;
    }
#pragma unroll
    for (int g=0; g<5; ++g){
      acc[g] += __shfl_xor(acc[g], 16);
      acc[g] += __shfl_xor(acc[g], 32);
    }
    if (p==0){
      float val[5];
#pragma unroll
      for (int g=0; g<5; ++g){
        float e = exp2_fast(acc[g]);         // = exp(-pre) or exp(-2*pre), SC-folded
        float s = rcpf(1.f + e);
        val[g] = is_g ? (2.f*s - 1.f) : s;   // sigmoid / tanh, NaN-safe
      }
      f4v v; v.x=val[0]; v.y=val[1]; v.z=val[2]; v.w=val[3];
      *(f4v*)&sm->gbuf[k*8] = v;
      sm->gbuf[k*8+4] = val[4];
    }
    __syncthreads();
    if (lin < NH){
      float ig = sm->gbuf[ai];
      float fg = sm->gbuf[ai+32];
      float gg = sm->gbuf[ai+64];
      float og = sm->gbuf[ai+96];
      float cn = fmaf(fg, c, ig*gg);
      c = cn;
      float e  = exp2_fast(cn*TC2);
      float th = 2.f*rcpf(1.f + e) - 1.f;
      float h  = og*th;
      // h pairs for the NEXT step's row
      ((_Float16*)&sm->xp[(t+1)&(CHK-1)][14])[lin] = (_Float16)h;
    }
  }
}

__global__ __launch_bounds__(64)
__attribute__((amdgpu_waves_per_eu(4,4)))
void lstm_vae_kernel(
  const float* __restrict__ x, const float* __restrict__ h0, const float* __restrict__ c0,
  const float* __restrict__ noise,
  const float* __restrict__ eWih, const float* __restrict__ eWhh, const float* __restrict__ ebih, const float* __restrict__ ebhh,
  const float* __restrict__ dWih, const float* __restrict__ dWhh, const float* __restrict__ dbih, const float* __restrict__ dbhh,
  const float* __restrict__ mW, const float* __restrict__ mb,
  const float* __restrict__ lW, const float* __restrict__ lb,
  const float* __restrict__ iW, const float* __restrict__ ib,
  const float* __restrict__ oW, const float* __restrict__ ob,
  float* __restrict__ out)
{
  __shared__ Smem sm;
  const int lane = threadIdx.x;
  const int p = lane>>4, k = lane&15, lin = lane;
  const int b = blockIdx.x;
  const float* xrow = x + (size_t)b*NT*NI;
  const bool is_g = ((k>>2)==2);
  const float L2E = 1.4426950408889634f;
  const float SC  = is_g ? (-2.f*L2E) : (-L2E);

  u32 w2[5][6]; float bias[5];
  u32 ow2[10] = {0,0,0,0,0,0,0,0,0,0};
  float obias = 0.f, c = 0.f;

  if (lin < NH){
    ((_Float16*)&sm.xp[0][14])[lin] = (_Float16)h0[(size_t)b*NH + lin];
    c = c0[(size_t)b*NH + lin];
  }
  load_w(eWih, eWhh, ebih, ebhh, p, k, SC, w2, bias);
  __syncthreads();

  lstm_loop<false>(xrow, &sm, lane, p, k, w2, bias, c, ow2, obias, nullptr);
  __syncthreads();   // final enc h pairs are in xp[0][14..23] (written at t=NT-1)

  const size_t OFF1 = (size_t)NB*NT*NI;
  const size_t OFF2 = OFF1 + (size_t)NB*NL;
  const size_t OFF3 = OFF2 + (size_t)NB*NL;
  const size_t OFF4 = OFF3 + (size_t)NB*NL;
  const size_t OFF5 = OFF4 + (size_t)NB*NH;

  if (lin < NH){
    out[OFF4 + (size_t)b*NH + lin] = (float)((_Float16*)&sm.xp[0][14])[lin];
    out[OFF5 + (size_t)b*NH + lin] = c;
  }
  if (lin < NL){
    float h[20];
#pragma unroll
    for (int j=0;j<10;++j){
      h2v hh = __builtin_bit_cast(h2v, sm.xp[0][14+j]);
      h[2*j] = (float)hh.x; h[2*j+1] = (float)hh.y;
    }
    float mm = mb[lin], lv = lb[lin];
#pragma unroll
    for (int j=0;j<20;++j){
      mm = fmaf(mW[lin*20+j], h[j], mm);
      lv = fmaf(lW[lin*20+j], h[j], lv);
    }
    float sd = __expf(0.5f*lv);
    float zz = fmaf(noise[(size_t)b*NL + lin], sd, mm);
    out[OFF1 + (size_t)b*NL + lin] = mm;
    out[OFF2 + (size_t)b*NL + lin] = lv;
    out[OFF3 + (size_t)b*NL + lin] = zz;
    sm.zbuf[lin] = zz;
  }
  __syncthreads();
  if (lin < NH){
    float hd = ib[lin];
#pragma unroll
    for (int l=0;l<NL;++l) hd = fmaf(iW[lin*NL+l], sm.zbuf[l], hd);
    c = hd;
    ((_Float16*)&sm.xp[0][14])[lin] = (_Float16)hd;   // decoder h for t=0
  }
  load_w(dWih, dWhh, dbih, dbhh, p, k, SC, w2, bias);
  if (lin < NI){
#pragma unroll
    for (int j=0;j<10;++j) ow2[j] = pk(oW[lin*20+2*j], oW[lin*20+2*j+1]);
    obias = ob[lin];
  }
#pragma unroll
  for (int j=0;j<10;++j) anchor_u(ow2[j]);
  __syncthreads();

  float* xhat = out + (size_t)b*NT*NI;
  lstm_loop<true>(xrow, &sm, lane, p, k, w2, bias, c, ow2, obias, xhat);
  __syncthreads();   // final dec h pairs in xp[0][14..23]

  if (lin < NI){
    const u32* hp = &sm.xp[0][14];
    float a = obias;
#pragma unroll
    for (int j=0;j<10;++j) a = fdot2(ow2[j], hp[j], a);
    xhat[(size_t)(NT-1)*NI + lin] = a;
  }
}

extern "C" void kernel_launch(void* const* d_in, const int* in_sizes, int n_in,
                              void* d_out, int out_size, void* d_ws, size_t ws_size,
                              hipStream_t stream) {
  const float* x     = (const float*)d_in[0];
  const float* h0    = (const float*)d_in[1];
  const float* c0    = (const float*)d_in[2];
  const float* noise = (const float*)d_in[3];
  const float* eWih  = (const float*)d_in[4];
  const float* eWhh  = (const float*)d_in[5];
  const float* ebih  = (const float*)d_in[6];
  const float* ebhh  = (const float*)d_in[7];
  const float* dWih  = (const float*)d_in[8];
  const float* dWhh  = (const float*)d_in[9];
  const float* dbih  = (const float*)d_in[10];
  const float* dbhh  = (const float*)d_in[11];
  const float* mW    = (const float*)d_in[12];
  const float* mb    = (const float*)d_in[13];
  const float* lW    = (const float*)d_in[14];
  const float* lb    = (const float*)d_in[15];
  const float* iW    = (const float*)d_in[16];
  const float* ib    = (const float*)d_in[17];
  const float* oW    = (const float*)d_in[18];
  const float* ob    = (const float*)d_in[19];
  float* out = (float*)d_out;

  hipLaunchKernelGGL(lstm_vae_kernel, dim3(NB), dim3(64), 0, stream,
                     x, h0, c0, noise,
                     eWih, eWhh, ebih, ebhh,
                     dWih, dWhh, dbih, dbhh,
                     mW, mb, lW, lb, iW, ib, oW, ob, out);
}